// Round 2
// baseline (186.944 us; speedup 1.0000x reference)
//
#include <hip/hip_runtime.h>
#include <cstdint>
#include <cstddef>

#define AS1 __attribute__((address_space(1)))
#define AS3 __attribute__((address_space(3)))

typedef __attribute__((ext_vector_type(4))) float f32x4;
typedef __attribute__((ext_vector_type(8))) short bf16x8;   // 8 bf16 in 4 VGPRs
typedef unsigned short u16;
typedef unsigned int u32;

#define B_ 2
#define S_ 2048
#define E_ 1024
#define H_ 16
#define D_ 64
#define M_ 4096  /* B_*S_ */

__device__ __forceinline__ u16 f2bf(float f) {
  union { float f; u32 u; } v; v.f = f;
  u32 u = v.u;
  u32 r = (u + 0x7FFFu + ((u >> 16) & 1u)) >> 16;   // RNE
  return (u16)r;
}
__device__ __forceinline__ float bf2f(u16 h) {
  union { u32 u; float f; } v; v.u = ((u32)h) << 16;
  return v.f;
}

__device__ __forceinline__ void gl2lds16(const void* g, void* l) {
  __builtin_amdgcn_global_load_lds((const AS1 void*)g, (AS3 void*)l, 16, 0, 0);
}

// ---------------------------------------------------------------------------
// prep: fp32 -> bf16 conversions (x, Wq|Wk|Wv concat, Wo) + rope cos/sin table
// ---------------------------------------------------------------------------
__global__ __launch_bounds__(256) void prep_kernel(
    const float* __restrict__ x, const float* __restrict__ wq,
    const float* __restrict__ wk, const float* __restrict__ wv,
    const float* __restrict__ wo,
    u16* __restrict__ xb, u16* __restrict__ wqkv, u16* __restrict__ wob,
    float* __restrict__ ctab, float* __restrict__ stab)
{
  int idx = blockIdx.x * 256 + threadIdx.x;
  const int NX4 = (M_ * E_) / 4;          // 1048576 float4s of x
  const int NW4 = (E_ * E_) / 4;          // 262144 per weight
  const int CONV_TOTAL = NX4 + 4 * NW4;   // 2097152
  if (idx < CONV_TOTAL) {
    const float* src; u16* dst; int off;
    if (idx < NX4)                { src = x;  dst = xb;              off = idx; }
    else if (idx < NX4 + NW4)     { src = wq; dst = wqkv;            off = idx - NX4; }
    else if (idx < NX4 + 2 * NW4) { src = wk; dst = wqkv + E_ * E_;  off = idx - NX4 - NW4; }
    else if (idx < NX4 + 3 * NW4) { src = wv; dst = wqkv + 2 * E_ * E_; off = idx - NX4 - 2 * NW4; }
    else                          { src = wo; dst = wob;             off = idx - NX4 - 3 * NW4; }
    float4 v = reinterpret_cast<const float4*>(src)[off];
    ushort4 o;
    o.x = f2bf(v.x); o.y = f2bf(v.y); o.z = f2bf(v.z); o.w = f2bf(v.w);
    reinterpret_cast<ushort4*>(dst)[off] = o;
  } else if (idx < CONV_TOTAL + S_ * 32) {
    int e = idx - CONV_TOTAL;
    int s = e >> 5, i = e & 31;
    double invf = pow(10000.0, -(double)i / 32.0);
    double ang = (double)s * invf;
    ctab[e] = (float)cos(ang);
    stab[e] = (float)sin(ang);
  }
}

// ---------------------------------------------------------------------------
// GEMM: C[m,n] = sum_k A[m,k] * B[n,k]   (both K-contiguous, K=1024)
// 128x128 tile, BK=64, 4 waves (2x2 of 64x64), 16x16x32 bf16 MFMA,
// global_load_lds(16B) with st-style XOR swizzle (pre-swizzled source).
// MODE 0: N=3072 QKV fused -> Q,K [B,H,S,D] bf16 ; V transposed [B,H,D,S]
// MODE 1: N=1024 out-proj  -> fp32 out [M,E]
// ---------------------------------------------------------------------------
template <int MODE>
__global__ __launch_bounds__(256) void gemm_bt(
    const u16* __restrict__ A, const u16* __restrict__ Bm,
    u16* __restrict__ q_out, u16* __restrict__ k_out, u16* __restrict__ vt_out,
    float* __restrict__ f_out)
{
  __shared__ __align__(16) u16 lA[128 * 64];
  __shared__ __align__(16) u16 lB[128 * 64];
  const int tid = threadIdx.x;
  const int w = tid >> 6, l = tid & 63;
  const int lr = l & 15, lg = l >> 4;
  const int mt = blockIdx.y, nt = blockIdx.x;
  const int woffm = (w >> 1) * 64, woffn = (w & 1) * 64;

  // staging: chunk = 1KB = 8 rows of 128B; lane l -> row l>>3, 16B slot l&7.
  // LDS dest is linear; source column is inverse-swizzled so that a swizzled
  // ds_read gets logical data (rule #21: both-sides-or-neither).
  const int srow = l >> 3;                   // 0..7 within chunk
  const int scol = ((l & 7) ^ srow) * 8;     // source column (elements)
  const u16* Abase = A + (size_t)(mt * 128) * 1024;
  const u16* Bbase = Bm + (size_t)(nt * 128) * 1024;

  f32x4 acc[4][4];
#pragma unroll
  for (int i = 0; i < 4; ++i)
#pragma unroll
    for (int j = 0; j < 4; ++j) acc[i][j] = (f32x4){0.f, 0.f, 0.f, 0.f};

  for (int kt = 0; kt < 1024; kt += 64) {
    __syncthreads();                 // previous compute done before overwrite
#pragma unroll
    for (int i = 0; i < 4; ++i) {
      int ch = w * 4 + i;            // 16 chunks cover 128x64
      int row = ch * 8 + srow;
      gl2lds16(Abase + row * 1024 + kt + scol, &lA[ch * 512]);
      gl2lds16(Bbase + row * 1024 + kt + scol, &lB[ch * 512]);
    }
    __syncthreads();                 // vmcnt(0) drain -> tiles ready
#pragma unroll
    for (int kk = 0; kk < 2; ++kk) {
      bf16x8 av[4], bv[4];
#pragma unroll
      for (int mf = 0; mf < 4; ++mf) {
        int row = woffm + mf * 16 + lr;
        int byteoff = row * 128 + ((kk * 64 + lg * 16) ^ ((row & 7) << 4));
        av[mf] = *(const bf16x8*)((const char*)lA + byteoff);
      }
#pragma unroll
      for (int nf = 0; nf < 4; ++nf) {
        int row = woffn + nf * 16 + lr;
        int byteoff = row * 128 + ((kk * 64 + lg * 16) ^ ((row & 7) << 4));
        bv[nf] = *(const bf16x8*)((const char*)lB + byteoff);
      }
#pragma unroll
      for (int mf = 0; mf < 4; ++mf)
#pragma unroll
        for (int nf = 0; nf < 4; ++nf)
          acc[mf][nf] = __builtin_amdgcn_mfma_f32_16x16x32_bf16(
              av[mf], bv[nf], acc[mf][nf], 0, 0, 0);
    }
  }

  if (MODE == 0) {
    // C col n in [0,3072): wsel = n>>10 (0=Q,1=K,2=V); h=(n>>6)&15; d=n&63
    // C/D layout: col = lane&15, row = (lane>>4)*4 + reg  [m89-verified]
#pragma unroll
    for (int mf = 0; mf < 4; ++mf) {
      int sbase = mt * 128 + woffm + mf * 16 + lg * 4;   // global m for reg 0
      int b = sbase >> 11, s = sbase & 2047;             // 4 regs stay in-batch
#pragma unroll
      for (int nf = 0; nf < 4; ++nf) {
        int n = nt * 128 + woffn + nf * 16 + lr;
        int wsel = n >> 10, r = n & 1023, hh = r >> 6, d = r & 63;
        if (wsel == 2) {
          ushort4 pk;
          pk.x = f2bf(acc[mf][nf][0]); pk.y = f2bf(acc[mf][nf][1]);
          pk.z = f2bf(acc[mf][nf][2]); pk.w = f2bf(acc[mf][nf][3]);
          *reinterpret_cast<ushort4*>(
              vt_out + ((size_t)(b * 16 + hh) * 64 + d) * 2048 + s) = pk;
        } else {
          u16* dst = (wsel == 0 ? q_out : k_out) +
                     ((size_t)(b * 16 + hh) * 2048) * 64 + d;
#pragma unroll
          for (int rr = 0; rr < 4; ++rr)
            dst[(size_t)(s + rr) * 64] = f2bf(acc[mf][nf][rr]);
        }
      }
    }
  } else {
#pragma unroll
    for (int mf = 0; mf < 4; ++mf) {
      int m = mt * 128 + woffm + mf * 16 + lg * 4;
#pragma unroll
      for (int nf = 0; nf < 4; ++nf) {
        int n = nt * 128 + woffn + nf * 16 + lr;
#pragma unroll
        for (int rr = 0; rr < 4; ++rr)
          f_out[(size_t)(m + rr) * 1024 + n] = acc[mf][nf][rr];
      }
    }
  }
}

// ---------------------------------------------------------------------------
// RoPE in-place on Q,K bf16 [B,H,S,D]; each thread rotates the (d, d+32) pair
// ---------------------------------------------------------------------------
__global__ __launch_bounds__(256) void rope_apply(
    u16* __restrict__ qb, u16* __restrict__ kb,
    const float* __restrict__ ctab, const float* __restrict__ stab)
{
  int tid = blockIdx.x * 256 + threadIdx.x;   // B_*H_*S_*32 = 2097152 exact
  int d = tid & 31;
  int s = (tid >> 5) & 2047;
  int bh = tid >> 16;
  size_t base = ((size_t)bh * 2048 + s) * 64;
  float c = ctab[s * 32 + d], sn = stab[s * 32 + d];
  u16* qp = qb + base; u16* kp = kb + base;
  float q1 = bf2f(qp[d]), q2 = bf2f(qp[d + 32]);
  qp[d]      = f2bf(q1 * c - q2 * sn);
  qp[d + 32] = f2bf(q2 * c + q1 * sn);
  float k1 = bf2f(kp[d]), k2 = bf2f(kp[d + 32]);
  kp[d]      = f2bf(k1 * c - k2 * sn);
  kp[d + 32] = f2bf(k2 * c + k1 * sn);
}

// ---------------------------------------------------------------------------
// Banded causal attention, window 256. One wave = 16 query rows.
// K,V read directly from global (L2-resident); 32-key tiles; online softmax.
// Q [B,H,S,D] bf16 ; K [B,H,S,D] bf16 ; V transposed [B,H,D,S] bf16.
// Output y bf16 in [B,S,H*D] layout (GEMM-ready).
// ---------------------------------------------------------------------------
__global__ __launch_bounds__(256) void attn_kernel(
    const u16* __restrict__ qb, const u16* __restrict__ kb,
    const u16* __restrict__ vt, u16* __restrict__ yb)
{
  int blk = blockIdx.x;                  // b*512 + h*32 + qt
  int qt = blk & 31, h = (blk >> 5) & 15, b = blk >> 9;
  int w = threadIdx.x >> 6, l = threadIdx.x & 63;
  int lr = l & 15, lg = l >> 4;
  int qbase = qt * 64 + w * 16;

  const u16* Q  = qb + ((size_t)(b * 16 + h) * 2048) * 64;
  const u16* Kp = kb + ((size_t)(b * 16 + h) * 2048) * 64;
  const u16* Vp = vt + ((size_t)(b * 16 + h) * 64) * 2048;

  __shared__ __align__(16) u16 lds_p[4][16 * 40];  // per-wave P buffer, 40-elem rows
  u16* myp = &lds_p[w][0];

  // Q A-fragments: m = lane&15 (q row), k = (lane>>4)*8+j (d)
  bf16x8 aq0 = *(const bf16x8*)(Q + (size_t)(qbase + lr) * 64 + lg * 8);
  bf16x8 aq1 = *(const bf16x8*)(Q + (size_t)(qbase + lr) * 64 + 32 + lg * 8);

  f32x4 o[4];
#pragma unroll
  for (int i = 0; i < 4; ++i) o[i] = (f32x4){0.f, 0.f, 0.f, 0.f};
  float mrun[4], lrun[4];
#pragma unroll
  for (int r = 0; r < 4; ++r) { mrun[r] = -1e30f; lrun[r] = 0.f; }

  int kstart = qbase - 255; if (kstart < 0) kstart = 0;
  kstart &= ~31;
  int kend = qbase + 16;                 // exclusive
  const float scale = 0.125f;

  for (int kt = kstart; kt < kend; kt += 32) {
    // K B-fragments: n = lane&15 (key), k = (lane>>4)*8+j (d)
    bf16x8 bk0a = *(const bf16x8*)(Kp + (size_t)(kt + lr) * 64 + lg * 8);
    bf16x8 bk0b = *(const bf16x8*)(Kp + (size_t)(kt + lr) * 64 + 32 + lg * 8);
    bf16x8 bk1a = *(const bf16x8*)(Kp + (size_t)(kt + 16 + lr) * 64 + lg * 8);
    bf16x8 bk1b = *(const bf16x8*)(Kp + (size_t)(kt + 16 + lr) * 64 + 32 + lg * 8);
    f32x4 s0 = (f32x4){0.f, 0.f, 0.f, 0.f};
    f32x4 s1 = (f32x4){0.f, 0.f, 0.f, 0.f};
    s0 = __builtin_amdgcn_mfma_f32_16x16x32_bf16(aq0, bk0a, s0, 0, 0, 0);
    s0 = __builtin_amdgcn_mfma_f32_16x16x32_bf16(aq1, bk0b, s0, 0, 0, 0);
    s1 = __builtin_amdgcn_mfma_f32_16x16x32_bf16(aq0, bk1a, s1, 0, 0, 0);
    s1 = __builtin_amdgcn_mfma_f32_16x16x32_bf16(aq1, bk1b, s1, 0, 0, 0);

    float p0[4], p1[4], sf[4];
#pragma unroll
    for (int r = 0; r < 4; ++r) {
      int q = qbase + lg * 4 + r;
      int k0 = kt + lr, k1 = k0 + 16;
      int r0 = q - k0, r1 = q - k1;
      float v0 = (r0 >= 0 && r0 < 256) ? s0[r] * scale : -1e30f;
      float v1 = (r1 >= 0 && r1 < 256) ? s1[r] * scale : -1e30f;
      float mx = fmaxf(v0, v1);
      mx = fmaxf(mx, __shfl_xor(mx, 1));
      mx = fmaxf(mx, __shfl_xor(mx, 2));
      mx = fmaxf(mx, __shfl_xor(mx, 4));
      mx = fmaxf(mx, __shfl_xor(mx, 8));
      float mnew = fmaxf(mrun[r], mx);
      float f = __expf(mrun[r] - mnew);   // finite-mask trick: garbage rows
      mrun[r] = mnew;                     // flushed by f==0 when real key lands
      p0[r] = __expf(v0 - mnew);
      p1[r] = __expf(v1 - mnew);
      float sm = p0[r] + p1[r];
      sm += __shfl_xor(sm, 1);
      sm += __shfl_xor(sm, 2);
      sm += __shfl_xor(sm, 4);
      sm += __shfl_xor(sm, 8);
      lrun[r] = lrun[r] * f + sm;
      sf[r] = f;
    }
#pragma unroll
    for (int nf = 0; nf < 4; ++nf)
#pragma unroll
      for (int r = 0; r < 4; ++r) o[nf][r] *= sf[r];

    // P (acc layout: row=(lg*4+r), col=lr) -> LDS -> A-fragment layout
#pragma unroll
    for (int r = 0; r < 4; ++r) {
      myp[(lg * 4 + r) * 40 + lr]      = f2bf(p0[r]);
      myp[(lg * 4 + r) * 40 + 16 + lr] = f2bf(p1[r]);
    }
    asm volatile("s_waitcnt lgkmcnt(0)" ::: "memory");
    bf16x8 pa = *(const bf16x8*)((const char*)myp + lr * 80 + lg * 16);
    asm volatile("s_waitcnt lgkmcnt(0)" ::: "memory");  // read done before next overwrite

    // PV: B-fragments from V^T: n = lane&15 (d), k = (lane>>4)*8+j (key)
#pragma unroll
    for (int df = 0; df < 4; ++df) {
      bf16x8 vv = *(const bf16x8*)(Vp + (size_t)(df * 16 + lr) * 2048 + kt + lg * 8);
      o[df] = __builtin_amdgcn_mfma_f32_16x16x32_bf16(pa, vv, o[df], 0, 0, 0);
    }
  }

#pragma unroll
  for (int r = 0; r < 4; ++r) lrun[r] = 1.f / lrun[r];
#pragma unroll
  for (int df = 0; df < 4; ++df)
#pragma unroll
    for (int r = 0; r < 4; ++r) {
      int s = qbase + lg * 4 + r;
      int d = df * 16 + lr;
      yb[((size_t)(b * 2048 + s)) * 1024 + h * 64 + d] = f2bf(o[df][r] * lrun[r]);
    }
}

// ---------------------------------------------------------------------------
extern "C" void kernel_launch(void* const* d_in, const int* in_sizes, int n_in,
                              void* d_out, int out_size, void* d_ws, size_t ws_size,
                              hipStream_t stream) {
  const float* x  = (const float*)d_in[0];
  const float* wq = (const float*)d_in[1];
  const float* wk = (const float*)d_in[2];
  const float* wv = (const float*)d_in[3];
  const float* wo = (const float*)d_in[4];

  // workspace layout (48.5 MB)
  char* ws = (char*)d_ws;
  const size_t MB = 1u << 20;
  if (ws_size < 49 * MB) return;  // not enough scratch: fail cleanly
  u16*   xb   = (u16*)(ws);                 // 8 MB  x bf16 [4096,1024]
  u16*   wqkv = (u16*)(ws + 8 * MB);        // 6 MB  Wq|Wk|Wv bf16 [3072,1024]
  u16*   wob  = (u16*)(ws + 14 * MB);       // 2 MB  Wo bf16 [1024,1024]
  u16*   qb   = (u16*)(ws + 16 * MB);       // 8 MB  Q bf16 [B,H,S,D]
  u16*   kb   = (u16*)(ws + 24 * MB);       // 8 MB  K bf16 [B,H,S,D]
  u16*   vt   = (u16*)(ws + 32 * MB);       // 8 MB  V^T bf16 [B,H,D,S]
  u16*   yb   = (u16*)(ws + 40 * MB);       // 8 MB  attn out bf16 [B,S,E]
  float* ct   = (float*)(ws + 48 * MB);     // 256 KB cos table [S,32]
  float* st   = (float*)(ws + 48 * MB + 256 * 1024);
  float* out  = (float*)d_out;

  prep_kernel<<<8448, 256, 0, stream>>>(x, wq, wk, wv, wo, xb, wqkv, wob, ct, st);
  gemm_bt<0><<<dim3(24, 32), 256, 0, stream>>>(xb, wqkv, qb, kb, vt, nullptr);
  rope_apply<<<8192, 256, 0, stream>>>(qb, kb, ct, st);
  attn_kernel<<<1024, 256, 0, stream>>>(qb, kb, vt, yb);
  gemm_bt<1><<<dim3(8, 32), 256, 0, stream>>>(yb, wob, nullptr, nullptr, nullptr, out);
}